// Round 21
// baseline (279.585 us; speedup 1.0000x reference)
//
#include <hip/hip_runtime.h>
#include <hip/hip_bf16.h>

using f32x4  = __attribute__((ext_vector_type(4))) float;
using bf16x8 = __attribute__((ext_vector_type(8))) short;
using bf16x4 = __attribute__((ext_vector_type(4))) short;
using u32x2  = __attribute__((ext_vector_type(2))) unsigned int;
using u32x4  = __attribute__((ext_vector_type(4))) unsigned int;

__device__ __forceinline__ float bf2f(short s) {
    unsigned u = ((unsigned)(unsigned short)s) << 16;
    return __builtin_bit_cast(float, u);
}
__device__ __forceinline__ unsigned short f2b(float f) {
    unsigned u = __builtin_bit_cast(unsigned, f);
    unsigned r = u + 0x7FFFu + ((u >> 16) & 1u);   // RNE
    return (unsigned short)(r >> 16);
}
__device__ __forceinline__ short f2b_hw(float f) {
    __hip_bfloat16 h = __float2bfloat16(f);        // RNE; pairs fuse to v_cvt_pk_bf16_f32
    return *reinterpret_cast<short*>(&h);
}
__device__ __forceinline__ void gl_lds16(const void* g, void* l) {
    __builtin_amdgcn_global_load_lds((const __attribute__((address_space(1))) void*)g,
                                     (__attribute__((address_space(3))) void*)l, 16, 0, 0);
}

// ---------------- weight convert ----------------
__global__ void k_wconv(const float* __restrict__ wq, const float* __restrict__ wp,
                        unsigned short* __restrict__ out) {
    int i = blockIdx.x * 256 + threadIdx.x;       // 1024 blocks -> 262144
    float v = (i < 196608) ? wq[i] : wp[i - 196608];
    out[i] = f2b(v);
}

// ---------------- k_qkv15: counted-vmcnt pipeline at R12 occupancy ----------------
// A: fp32 loads -> regs issued a phase early; cvt; ds_write into SINGLE 16KB bf16 buf.
// B: global_load_lds into 2x16KB dbuf, issued a phase early. 48KB total -> 3 blocks/CU.
// Raw s_barrier + vmcnt(12): B(ks+1) DMA + xv(ks+1) loads stay in flight across compute(ks).
// Strip map (R12-verified: FETCH ~178MB, parallel HBM streams + per-XCD L2 reuse).
__global__ __launch_bounds__(256, 3) void k_qkv15(
    const float* __restrict__ x,               // fp32 [147456][256]
    const unsigned short* __restrict__ wqkv,   // bf16 [768][256]
    unsigned short* __restrict__ qkv)          // bf16 [147456][768]
{
    __shared__ unsigned short As[128 * 64];    // 16 KB; As[r][c]=A[r][c^(r&7)] (c=8-elem chunk)
    __shared__ unsigned short Bs[2][128 * 64]; // 2x16 KB; same swizzle
    const int tid = threadIdx.x;
    const int wv = tid >> 6, ln = tid & 63;
    const int lr = ln & 15, lk = ln >> 4;
    const int l8 = ln >> 3, c8 = ln & 7;

    // strip-chunked mapping: 6912 = 8 XCD-chunks x (6 strips x (6 n x 24 m))
    const int b = blockIdx.x;
    const int xcd = b & 7, local = b >> 3;
    const int strip = local / 144, r = local % 144;
    const int n0 = (r / 24) * 128;
    const size_t m0 = (size_t)(xcd * 144 + strip * 24 + (r % 24)) * 128;
    const int mq = (wv >> 1) * 64, nq = (wv & 1) * 64;

    f32x4 xv[8];                               // in-flight A slice (32 VGPR)

#define XLOAD(KS)                                                              \
    {                                                                          \
        _Pragma("unroll")                                                      \
        for (int p = 0; p < 4; ++p) {                                          \
            int row = wv * 32 + p * 8 + l8;                                    \
            const f32x4* src = (const f32x4*)(x + (m0 + row) * 256 + (KS) * 64 + c8 * 8); \
            xv[p * 2]     = src[0];                                            \
            xv[p * 2 + 1] = src[1];                                            \
        }                                                                      \
    }
#define AWRITE()                                                               \
    {                                                                          \
        _Pragma("unroll")                                                      \
        for (int p = 0; p < 4; ++p) {                                          \
            int row = wv * 32 + p * 8 + l8;                                    \
            bf16x8 v;                                                          \
            _Pragma("unroll")                                                  \
            for (int j = 0; j < 4; ++j) {                                      \
                v[j]     = f2b_hw(xv[p * 2][j]);                               \
                v[4 + j] = f2b_hw(xv[p * 2 + 1][j]);                           \
            }                                                                  \
            *(bf16x8*)&As[row * 64 + ((c8 ^ (row & 7)) * 8)] = v;              \
        }                                                                      \
    }
#define BSTAGE(KS, BUF)                                                        \
    {                                                                          \
        _Pragma("unroll")                                                      \
        for (int i = 0; i < 4; ++i) {                                          \
            int r8 = i * 8 + l8;                                               \
            int sc = (c8 ^ (r8 & 7)) * 8;                                      \
            gl_lds16(wqkv + (size_t)(n0 + wv * 32 + r8) * 256 + (KS) * 64 + sc,\
                     &Bs[BUF][(wv * 32 + i * 8) * 64]);                        \
        }                                                                      \
    }

    f32x4 acc[4][4];
#pragma unroll
    for (int mi = 0; mi < 4; ++mi)
#pragma unroll
        for (int ni = 0; ni < 4; ++ni) {
            f32x4 z = {0.f, 0.f, 0.f, 0.f};
            acc[mi][ni] = z;
        }

    // prologue: fill phase 0
    XLOAD(0);
    BSTAGE(0, 0);
    AWRITE();                                  // dep-waits its own xv loads
    asm volatile("s_waitcnt vmcnt(0)" ::: "memory");    // B(0) DMA done
    asm volatile("s_waitcnt lgkmcnt(0)" ::: "memory");  // As writes done
    __builtin_amdgcn_s_barrier();

    int curb = 0;
#pragma unroll 1
    for (int ks = 0; ks < 4; ++ks) {
        if (ks < 3) {
            XLOAD(ks + 1);                     // 8 reg-loads, fly across compute
            BSTAGE(ks + 1, curb ^ 1);          // 4 DMA into alt buf, fly across compute
            // outstanding: 4 old (B(ks)) + 12 new; keep 12 newest in flight
            asm volatile("s_waitcnt vmcnt(12)" ::: "memory");
            __builtin_amdgcn_s_barrier();      // B(ks) + As(ks) visible to all waves
        }
        // (ks==3: B(3) already proven complete by iter-2's vmcnt(12)? No: B(3) issued
        //  in iter 2; its completion is forced below.)
        if (ks == 3) {
            asm volatile("s_waitcnt vmcnt(0)" ::: "memory");
            __builtin_amdgcn_s_barrier();
        }

        // compute(ks) from As + Bs[curb]
#pragma unroll
        for (int kk = 0; kk < 2; ++kk) {
            bf16x8 av[4], bv[4];
#pragma unroll
            for (int i = 0; i < 4; ++i) {
                int ar = mq + i * 16 + lr;
                av[i] = *(const bf16x8*)&As[ar * 64 + (((kk * 4 + lk) ^ (ar & 7)) * 8)];
                int br = nq + i * 16 + lr;
                bv[i] = *(const bf16x8*)&Bs[curb][br * 64 + (((kk * 4 + lk) ^ (br & 7)) * 8)];
            }
#pragma unroll
            for (int mi = 0; mi < 4; ++mi)
#pragma unroll
                for (int ni = 0; ni < 4; ++ni)
                    acc[mi][ni] = __builtin_amdgcn_mfma_f32_16x16x32_bf16(bv[ni], av[mi], acc[mi][ni], 0, 0, 0);
        }

        if (ks < 3) {
            __builtin_amdgcn_s_barrier();      // all waves done reading As(ks)
            AWRITE();                          // overwrite As with ks+1 (waits its xv only)
            asm volatile("s_waitcnt lgkmcnt(0)" ::: "memory");
            // next iteration's barrier publishes these writes
        }
        curb ^= 1;
    }

#undef XLOAD
#undef AWRITE
#undef BSTAGE

    // C: row = m0+mq+mi*16+lr, cols n0+nq+ni*16+lk*4..+3
#pragma unroll
    for (int mi = 0; mi < 4; ++mi) {
        const size_t row = m0 + mq + mi * 16 + lr;
#pragma unroll
        for (int ni = 0; ni < 4; ++ni) {
            u32x2 u;
            u[0] = (unsigned)f2b(acc[mi][ni][0]) | ((unsigned)f2b(acc[mi][ni][1]) << 16);
            u[1] = (unsigned)f2b(acc[mi][ni][2]) | ((unsigned)f2b(acc[mi][ni][3]) << 16);
            *(u32x2*)(qkv + row * 768 + n0 + nq + ni * 16 + lk * 4) = u;
        }
    }
}

// ---------------- k_attn: block = (b*32+wh, half, head), 16 windows ----------------
__global__ __launch_bounds__(256) void k_attn(
    unsigned short* __restrict__ qkv)          // bf16 [147456][768]; q region overwritten
{
    constexpr int LQ = 68;
    __shared__ unsigned short Ks[144 * LQ];
    __shared__ unsigned short Vs[144 * LQ];
    const int tid = threadIdx.x;
    const int t3 = blockIdx.x;                 // b*32 + wh
    const int hf = blockIdx.y;                 // 0..1
    const int h  = blockIdx.z;                 // 0..3
    const int bb = t3 >> 5, wh = t3 & 31;

    for (int idx = tid; idx < 1152; idx += 256) {
        int row = idx >> 3, ch = idx & 7;
        int ww = row / 9, t = row - ww * 9;
        int rr = t / 3, cc = t - rr * 3;
        size_t xrow = (size_t)bb * 9216 + (wh * 3 + rr) * 96 + hf * 48 + ww * 3 + cc;
        *(bf16x8*)&Ks[row * LQ + ch * 8] = *(const bf16x8*)(qkv + xrow * 768 + 256 + h * 64 + ch * 8);
        *(bf16x8*)&Vs[row * LQ + ch * 8] = *(const bf16x8*)(qkv + xrow * 768 + 512 + h * 64 + ch * 8);
    }
    __syncthreads();

#pragma unroll 1
    for (int pass = 0; pass < 2; ++pass) {
        int row;
        bool act;
        if (pass == 0) { row = tid >> 1;            act = true; }
        else           { row = 128 + (tid >> 1);    act = tid < 32; }
        if (act) {
            const int hc = tid & 1;
            const int w9 = (row / 9) * 9;
            int t = row - w9;
            int rr = t / 3, cc = t - rr * 3;
            size_t xrow = (size_t)bb * 9216 + (wh * 3 + rr) * 96 + hf * 48 + (w9 / 9) * 3 + cc;
            unsigned short* qp = qkv + xrow * 768 + h * 64 + hc * 32;
            float q[32];
#pragma unroll
            for (int g = 0; g < 4; ++g) {
                bf16x8 v = *(const bf16x8*)(qp + g * 8);
#pragma unroll
                for (int j = 0; j < 8; ++j) q[g * 8 + j] = bf2f(v[j]);
            }
            float s[9];
#pragma unroll
            for (int kk = 0; kk < 9; ++kk) {
                float acc = 0.f;
#pragma unroll
                for (int g = 0; g < 4; ++g) {
                    bf16x8 v = *(const bf16x8*)&Ks[(w9 + kk) * LQ + hc * 32 + g * 8];
#pragma unroll
                    for (int j = 0; j < 8; ++j) acc += q[g * 8 + j] * bf2f(v[j]);
                }
                s[kk] = acc;
            }
#pragma unroll
            for (int kk = 0; kk < 9; ++kk)
                s[kk] = (s[kk] + __shfl_xor(s[kk], 1)) * 0.125f;   // 1/sqrt(64)
            float m = s[0];
#pragma unroll
            for (int kk = 1; kk < 9; ++kk) m = fmaxf(m, s[kk]);
            float sum = 0.f;
#pragma unroll
            for (int kk = 0; kk < 9; ++kk) { s[kk] = __expf(s[kk] - m); sum += s[kk]; }
            float inv = 1.f / sum;
            float o[32];
#pragma unroll
            for (int d = 0; d < 32; ++d) o[d] = 0.f;
#pragma unroll
            for (int kk = 0; kk < 9; ++kk) {
                float pk = s[kk] * inv;
#pragma unroll
                for (int g = 0; g < 4; ++g) {
                    bf16x8 v = *(const bf16x8*)&Vs[(w9 + kk) * LQ + hc * 32 + g * 8];
#pragma unroll
                    for (int j = 0; j < 8; ++j) o[g * 8 + j] += pk * bf2f(v[j]);
                }
            }
#pragma unroll
            for (int grp = 0; grp < 4; ++grp) {
                u32x4 u;
#pragma unroll
                for (int e = 0; e < 4; ++e) {
                    int i0 = grp * 8 + e * 2;
                    u[e] = (unsigned)f2b(o[i0]) | ((unsigned)f2b(o[i0 + 1]) << 16);
                }
                *(u32x4*)(qp + grp * 8) = u;
            }
        }
    }
}

// ---------------- k_proj: m97-style GEMM [147456][256](stride 768)@[256][256]^T -> fp32 out ----------------
__global__ __launch_bounds__(256) void k_proj(
    const unsigned short* __restrict__ ain,    // attn-out = q region of qkv, row stride 768
    const unsigned short* __restrict__ wproj,  // bf16 [256][256]
    float* __restrict__ out)
{
    __shared__ unsigned short As[128 * 64];
    __shared__ unsigned short Bs[128 * 64];
    const int tid = threadIdx.x;
    const int wv = tid >> 6, ln = tid & 63;
    const int lr = ln & 15, lk = ln >> 4;
    const int l8 = ln >> 3, c8 = ln & 7;

    int b = blockIdx.x;                        // 2304 = 1152 m-tiles x 2 n-chunks
    int w = (b & 7) * 288 + (b >> 3);
    const size_t m0 = (size_t)(w >> 1) * 128;
    const int n0 = (w & 1) * 128;
    const int mq = (wv >> 1) * 64, nq = (wv & 1) * 64;

    f32x4 acc[4][4];
#pragma unroll
    for (int mi = 0; mi < 4; ++mi)
#pragma unroll
        for (int ni = 0; ni < 4; ++ni) {
            f32x4 z = {0.f, 0.f, 0.f, 0.f};
            acc[mi][ni] = z;
        }

#pragma unroll 1
    for (int ks = 0; ks < 4; ++ks) {
        const int k0 = ks * 64;
        __syncthreads();
#pragma unroll
        for (int i = 0; i < 4; ++i) {
            int r8 = i * 8 + l8;
            int sc = (c8 ^ (r8 & 7)) * 8;
            gl_lds16(ain   + (m0 + wv * 32 + r8) * 768 + k0 + sc,
                     &As[(wv * 32 + i * 8) * 64]);
            gl_lds16(wproj + (size_t)(n0 + wv * 32 + r8) * 256 + k0 + sc,
                     &Bs[(wv * 32 + i * 8) * 64]);
        }
        __syncthreads();

#pragma unroll
        for (int kk = 0; kk < 2; ++kk) {
            bf16x8 av[4], bv[4];
#pragma unroll
            for (int i = 0; i < 4; ++i) {
                int ar = mq + i * 16 + lr;
                av[i] = *(const bf16x8*)&As[ar * 64 + (((kk * 4 + lk) ^ (ar & 7)) * 8)];
                int br = nq + i * 16 + lr;
                bv[i] = *(const bf16x8*)&Bs[br * 64 + (((kk * 4 + lk) ^ (br & 7)) * 8)];
            }
#pragma unroll
            for (int mi = 0; mi < 4; ++mi)
#pragma unroll
                for (int ni = 0; ni < 4; ++ni)
                    acc[mi][ni] = __builtin_amdgcn_mfma_f32_16x16x32_bf16(bv[ni], av[mi], acc[mi][ni], 0, 0, 0);
        }
    }

#pragma unroll
    for (int mi = 0; mi < 4; ++mi) {
        const size_t row = m0 + mq + mi * 16 + lr;
#pragma unroll
        for (int ni = 0; ni < 4; ++ni)
            *(f32x4*)&out[row * 256 + n0 + nq + ni * 16 + lk * 4] = acc[mi][ni];
    }
}

// ==================== FALLBACK (round-3 kernels, ~76 MB ws) ====================

__device__ __forceinline__ int grow_of(int wbase, int row) {
    int wi = row / 9;
    int t  = row - wi * 9;
    int w  = wbase + wi;
    if (w >= 16384) return -1;
    int b = w >> 10, rem = w & 1023;
    int wh = rem >> 5, ww = rem & 31;
    int r = t / 3, c = t - r * 3;
    return b * 9216 + (wh * 3 + r) * 96 + ww * 3 + c;
}

__global__ __launch_bounds__(256) void k_winattn_fb(
    const float* __restrict__ x,
    const unsigned short* __restrict__ wqkv,
    unsigned short* __restrict__ aout)
{
    constexpr int LDA = 264;
    constexpr int LQ  = 68;
    __shared__ unsigned short As[64 * LDA];
    __shared__ unsigned short Qb[3][64 * LQ];
    __shared__ int rowmap[64];

    const int tid = threadIdx.x;
    const int wbase = blockIdx.x * 7;
    const int wv = tid >> 6, ln = tid & 63;
    const int lr = ln & 15, lk = ln >> 4;
    const int mw = wv >> 1, nw = wv & 1;

    if (tid < 64)
        rowmap[tid] = (tid < 63) ? grow_of(wbase, tid) : -1;
    __syncthreads();

    for (int idx = tid; idx < 64 * 32; idx += 256) {
        int row = idx >> 5, g = idx & 31;
        int gr = rowmap[row];
        bf16x8 v;
        if (gr >= 0) {
            const f32x4* p = (const f32x4*)(x + (size_t)gr * 256 + g * 8);
            f32x4 f0 = p[0], f1 = p[1];
#pragma unroll
            for (int j = 0; j < 4; ++j) {
                v[j]     = (short)f2b(f0[j]);
                v[4 + j] = (short)f2b(f1[j]);
            }
        } else {
#pragma unroll
            for (int j = 0; j < 8; ++j) v[j] = 0;
        }
        *(bf16x8*)&As[row * LDA + g * 8] = v;
    }
    __syncthreads();

#pragma unroll 1
    for (int h = 0; h < 4; ++h) {
#pragma unroll 1
        for (int part = 0; part < 3; ++part) {
            const int j0 = part * 256 + h * 64 + nw * 32;
            bf16x8 w[2][8];
#pragma unroll
            for (int ni = 0; ni < 2; ++ni)
#pragma unroll
                for (int kk = 0; kk < 8; ++kk)
                    w[ni][kk] = *(const bf16x8*)(wqkv + (size_t)(j0 + ni * 16 + lr) * 256 + kk * 32 + lk * 8);

            f32x4 acc[2][2];
#pragma unroll
            for (int mi = 0; mi < 2; ++mi)
#pragma unroll
                for (int ni = 0; ni < 2; ++ni) {
                    f32x4 z = {0.f, 0.f, 0.f, 0.f};
                    acc[mi][ni] = z;
                }
#pragma unroll
            for (int kk = 0; kk < 8; ++kk) {
                const int k0 = kk * 32 + lk * 8;
                bf16x8 a0 = *(const bf16x8*)&As[(mw * 32 + lr) * LDA + k0];
                bf16x8 a1 = *(const bf16x8*)&As[(mw * 32 + 16 + lr) * LDA + k0];
                acc[0][0] = __builtin_amdgcn_mfma_f32_16x16x32_bf16(w[0][kk], a0, acc[0][0], 0, 0, 0);
                acc[1][0] = __builtin_amdgcn_mfma_f32_16x16x32_bf16(w[0][kk], a1, acc[1][0], 0, 0, 0);
                acc[0][1] = __builtin_amdgcn_mfma_f32_16x16x32_bf16(w[1][kk], a0, acc[0][1], 0, 0, 0);
                acc[1][1] = __builtin_amdgcn_mfma_f32_16x16x32_bf16(w[1][kk], a1, acc[1][1], 0, 0, 0);
            }
#pragma unroll
            for (int mi = 0; mi < 2; ++mi)
#pragma unroll
                for (int ni = 0; ni < 2; ++ni) {
                    int row = mw * 32 + mi * 16 + lr;
                    int col = nw * 32 + ni * 16 + lk * 4;
                    u32x2 u;
                    u[0] = (unsigned)f2b(acc[mi][ni][0]) | ((unsigned)f2b(acc[mi][ni][1]) << 16);
                    u[1] = (unsigned)f2b(acc[mi][ni][2]) | ((unsigned)f2b(acc[mi][ni][3]) << 16);
                    *(u32x2*)&Qb[part][row * LQ + col] = u;
                }
        }
        __syncthreads();
        {
            const int row = wv * 16 + lr;
            const int c   = lk;
            if (row < 63) {
                const int w9 = (row / 9) * 9;
                float q[16];
#pragma unroll
                for (int g = 0; g < 4; ++g) {
                    bf16x4 v = *(const bf16x4*)&Qb[0][row * LQ + c * 16 + g * 4];
#pragma unroll
                    for (int j = 0; j < 4; ++j) q[g * 4 + j] = bf2f(v[j]);
                }
                float s[9];
#pragma unroll
                for (int kk = 0; kk < 9; ++kk) {
                    float t = 0.f;
#pragma unroll
                    for (int g = 0; g < 4; ++g) {
                        bf16x4 v = *(const bf16x4*)&Qb[1][(w9 + kk) * LQ + c * 16 + g * 4];
#pragma unroll
                        for (int j = 0; j < 4; ++j) t += q[g * 4 + j] * bf2f(v[j]);
                    }
                    s[kk] = t;
                }
#pragma unroll
                for (int kk = 0; kk < 9; ++kk) {
                    float t = s[kk];
                    t += __shfl_xor(t, 16);
                    t += __shfl_xor(t, 32);
                    s[kk] = t * 0.125f;
                }
                float m = s[0];
#pragma unroll
                for (int kk = 1; kk < 9; ++kk) m = fmaxf(m, s[kk]);
                float sum = 0.f;
#pragma unroll
                for (int kk = 0; kk < 9; ++kk) { s[kk] = __expf(s[kk] - m); sum += s[kk]; }
                float inv = 1.f / sum;
                float o[16];
#pragma unroll
                for (int d = 0; d < 16; ++d) o[d] = 0.f;
#pragma unroll
                for (int kk = 0; kk < 9; ++kk) {
                    float pk = s[kk] * inv;
#pragma unroll
                    for (int g = 0; g < 4; ++g) {
                        bf16x4 v = *(const bf16x4*)&Qb[2][(w9 + kk) * LQ + c * 16 + g * 4];
#pragma unroll
                        for (int j = 0; j < 4; ++j) o[g * 4 + j] += pk * bf2f(v[j]);
                    }
                }
                const int gr = rowmap[row];
                if (gr >= 0) {
#pragma unroll
                    for (int half = 0; half < 2; ++half) {
                        u32x4 u;
#pragma unroll
                        for (int e = 0; e < 4; ++e) {
                            int i0 = half * 8 + e * 2;
                            u[e] = (unsigned)f2b(o[i0]) | ((unsigned)f2b(o[i0 + 1]) << 16);
                        }
                        *(u32x4*)(aout + (size_t)gr * 256 + h * 64 + c * 16 + half * 8) = u;
                    }
                }
            }
        }
        __syncthreads();
    }
}

__global__ __launch_bounds__(256) void k_proj_fb(
    const unsigned short* __restrict__ ain,
    const unsigned short* __restrict__ wproj,
    float* __restrict__ out)
{
    const int tid = threadIdx.x;
    const int wv = tid >> 6, ln = tid & 63;
    const int lr = ln & 15, lk = ln >> 4;
    const size_t row0 = (size_t)blockIdx.x * 128;

    bf16x8 af[2][8];
#pragma unroll
    for (int mi = 0; mi < 2; ++mi) {
        const size_t row = row0 + wv * 32 + mi * 16 + lr;
#pragma unroll
        for (int kk = 0; kk < 8; ++kk)
            af[mi][kk] = *(const bf16x8*)(ain + row * 256 + kk * 32 + lk * 8);
    }
#pragma unroll
    for (int nc = 0; nc < 4; ++nc) {
        const int j0 = nc * 64;
        f32x4 acc[2][4];
#pragma unroll
        for (int mi = 0; mi < 2; ++mi)
#pragma unroll
            for (int ni = 0; ni < 4; ++ni) {
                f32x4 z = {0.f, 0.f, 0.f, 0.f};
                acc[mi][ni] = z;
            }
#pragma unroll
        for (int kk = 0; kk < 8; ++kk) {
            bf16x8 w[4];
#pragma unroll
            for (int ni = 0; ni < 4; ++ni)
                w[ni] = *(const bf16x8*)(wproj + (size_t)(j0 + ni * 16 + lr) * 256 + kk * 32 + lk * 8);
#pragma unroll
            for (int ni = 0; ni < 4; ++ni) {
                acc[0][ni] = __builtin_amdgcn_mfma_f32_16x16x32_bf16(w[ni], af[0][kk], acc[0][ni], 0, 0, 0);
                acc[1][ni] = __builtin_amdgcn_mfma_f32_16x16x32_bf16(w[ni], af[1][kk], acc[1][ni], 0, 0, 0);
            }
        }
#pragma unroll
        for (int mi = 0; mi < 2; ++mi) {
            const size_t row = row0 + wv * 32 + mi * 16 + lr;
#pragma unroll
            for (int ni = 0; ni < 4; ++ni)
                *(f32x4*)&out[row * 256 + j0 + ni * 16 + lk * 4] = acc[mi][ni];
        }
    }
}

extern "C" void kernel_launch(void* const* d_in, const int* in_sizes, int n_in,
                              void* d_out, int out_size, void* d_ws, size_t ws_size,
                              hipStream_t stream) {
    const float* x  = (const float*)d_in[0];
    const float* wq = (const float*)d_in[1];
    const float* wp = (const float*)d_in[2];
    unsigned short* wsb     = (unsigned short*)d_ws;
    unsigned short* wqkv_b  = wsb;                 // 196608
    unsigned short* wproj_b = wsb + 196608;        //  65536
    float* out = (float*)d_out;

    k_wconv<<<1024, 256, 0, stream>>>(wq, wp, wsb);

    const size_t need = 524288ULL + 147456ULL * 768ULL * 2ULL;   // weights + qkv (~227 MB)
    if (ws_size >= need) {
        unsigned short* qkv = wsb + 262144;                 // bf16 [147456][768]
        k_qkv15<<<6912, 256, 0, stream>>>(x, wqkv_b, qkv);
        k_attn <<<dim3(512, 2, 4), 256, 0, stream>>>(qkv);
        k_proj <<<2304, 256, 0, stream>>>(qkv, wproj_b, out);
    } else {
        unsigned short* aout = wsb + 262144;                // bf16 [147456][256]
        k_winattn_fb<<<2341, 256, 0, stream>>>(x, wqkv_b, aout);
        k_proj_fb  <<<1152, 256, 0, stream>>>(aout, wproj_b, out);
    }
}

// Round 22
// 270.272 us; speedup vs baseline: 1.0345x; 1.0345x over previous
//
#include <hip/hip_runtime.h>
#include <hip/hip_bf16.h>

using f32x4  = __attribute__((ext_vector_type(4))) float;
using bf16x8 = __attribute__((ext_vector_type(8))) short;
using bf16x4 = __attribute__((ext_vector_type(4))) short;
using u32x2  = __attribute__((ext_vector_type(2))) unsigned int;
using u32x4  = __attribute__((ext_vector_type(4))) unsigned int;

__device__ __forceinline__ float bf2f(short s) {
    unsigned u = ((unsigned)(unsigned short)s) << 16;
    return __builtin_bit_cast(float, u);
}
__device__ __forceinline__ unsigned short f2b(float f) {
    unsigned u = __builtin_bit_cast(unsigned, f);
    unsigned r = u + 0x7FFFu + ((u >> 16) & 1u);   // RNE
    return (unsigned short)(r >> 16);
}
__device__ __forceinline__ short f2b_hw(float f) {
    __hip_bfloat16 h = __float2bfloat16(f);        // RNE; pairs fuse to v_cvt_pk_bf16_f32
    return *reinterpret_cast<short*>(&h);
}
__device__ __forceinline__ void gl_lds16(const void* g, void* l) {
    __builtin_amdgcn_global_load_lds((const __attribute__((address_space(1))) void*)g,
                                     (__attribute__((address_space(3))) void*)l, 16, 0, 0);
}

// ---------------- weight convert ----------------
__global__ void k_wconv(const float* __restrict__ wq, const float* __restrict__ wp,
                        unsigned short* __restrict__ out) {
    int i = blockIdx.x * 256 + threadIdx.x;       // 1024 blocks -> 262144
    float v = (i < 196608) ? wq[i] : wp[i - 196608];
    out[i] = f2b(v);
}

// ---------------- k_qkv6: fused cvt+GEMM, strip-chunked tile order (best: R12/R20) ----------------
// A fp32 DMA-staged (cvt on LDS read); B bf16 DMA; 0 conflicts; FETCH ~178MB.
__global__ __launch_bounds__(256, 3) void k_qkv6(
    const float* __restrict__ x,               // fp32 [147456][256]
    const unsigned short* __restrict__ wqkv,   // bf16 [768][256]
    unsigned short* __restrict__ qkv)          // bf16 [147456][768]
{
    __shared__ float          Asf[128 * 64];   // 32 KB; Asf[r][c] = A[r][c^(r&15)] (c = 16B chunk)
    __shared__ unsigned short Bs[128 * 64];    // 16 KB; Bs[r][c] = B[r][c^(r&7)]  (c = 8-elem chunk)
    const int tid = threadIdx.x;
    const int wv = tid >> 6, ln = tid & 63;
    const int lr = ln & 15, lk = ln >> 4;
    const int l8 = ln >> 3, c8 = ln & 7;
    const int l16 = ln >> 4, c16 = ln & 15;

    // strip-chunked mapping: 6912 = 8 XCD-chunks x (6 strips x (6 n x 24 m))
    const int b = blockIdx.x;
    const int xcd = b & 7, local = b >> 3;     // local in 0..863
    const int strip = local / 144, r = local % 144;
    const int n0 = (r / 24) * 128;
    const size_t m0 = (size_t)(xcd * 144 + strip * 24 + (r % 24)) * 128;
    const int mq = (wv >> 1) * 64, nq = (wv & 1) * 64;

    f32x4 acc[4][4];
#pragma unroll
    for (int mi = 0; mi < 4; ++mi)
#pragma unroll
        for (int ni = 0; ni < 4; ++ni) {
            f32x4 z = {0.f, 0.f, 0.f, 0.f};
            acc[mi][ni] = z;
        }

#pragma unroll 1
    for (int ks = 0; ks < 4; ++ks) {
        const int k0 = ks * 64;
        __syncthreads();                       // prev MFMA reads done
        // ---- stage B (bf16) via DMA, source-side swizzle ----
#pragma unroll
        for (int i = 0; i < 4; ++i) {
            int r8 = i * 8 + l8;
            int sc = (c8 ^ (r8 & 7)) * 8;
            gl_lds16(wqkv + (size_t)(n0 + wv * 32 + r8) * 256 + k0 + sc,
                     &Bs[(wv * 32 + i * 8) * 64]);
        }
        // ---- stage A (fp32) via DMA, source-side swizzle: 8 x 1KB per wave ----
#pragma unroll
        for (int i = 0; i < 8; ++i) {
            int row = wv * 32 + i * 4 + l16;   // 4 rows per instruction
            int sc = ((c16 ^ (row & 15)) << 2);   // f32 offset of swizzled 16B chunk
            gl_lds16(x + (m0 + row) * 256 + k0 + sc,
                     &Asf[(wv * 32 + i * 4) * 64]);
        }
        __syncthreads();                       // DMA drained, staged data visible

#pragma unroll
        for (int kk = 0; kk < 2; ++kk) {
            bf16x8 av[4], bv[4];
#pragma unroll
            for (int i = 0; i < 4; ++i) {
                int ar = mq + i * 16 + lr;
                int cb = kk * 8 + lk * 2;      // base 16B-chunk in f32 domain
                f32x4 lo = *(const f32x4*)&Asf[ar * 64 + ((cb ^ (ar & 15)) << 2)];
                f32x4 hi = *(const f32x4*)&Asf[ar * 64 + (((cb ^ 1) ^ (ar & 15)) << 2)];
                bf16x8 t;
#pragma unroll
                for (int j = 0; j < 4; ++j) {
                    t[j]     = f2b_hw(lo[j]);
                    t[4 + j] = f2b_hw(hi[j]);
                }
                av[i] = t;
                int br = nq + i * 16 + lr;
                bv[i] = *(const bf16x8*)&Bs[br * 64 + (((kk * 4 + lk) ^ (br & 7)) * 8)];
            }
#pragma unroll
            for (int mi = 0; mi < 4; ++mi)
#pragma unroll
                for (int ni = 0; ni < 4; ++ni)
                    acc[mi][ni] = __builtin_amdgcn_mfma_f32_16x16x32_bf16(bv[ni], av[mi], acc[mi][ni], 0, 0, 0);
        }
    }

    // C: row = m0+mq+mi*16+lr, cols n0+nq+ni*16+lk*4..+3
#pragma unroll
    for (int mi = 0; mi < 4; ++mi) {
        const size_t row = m0 + mq + mi * 16 + lr;
#pragma unroll
        for (int ni = 0; ni < 4; ++ni) {
            u32x2 u;
            u[0] = (unsigned)f2b(acc[mi][ni][0]) | ((unsigned)f2b(acc[mi][ni][1]) << 16);
            u[1] = (unsigned)f2b(acc[mi][ni][2]) | ((unsigned)f2b(acc[mi][ni][3]) << 16);
            *(u32x2*)(qkv + row * 768 + n0 + nq + ni * 16 + lk * 4) = u;
        }
    }
}

// ---------------- k_attn: block = (b*32+wh, half, head), 16 windows ----------------
__global__ __launch_bounds__(256) void k_attn(
    unsigned short* __restrict__ qkv)          // bf16 [147456][768]; q region overwritten
{
    constexpr int LQ = 68;
    __shared__ unsigned short Ks[144 * LQ];
    __shared__ unsigned short Vs[144 * LQ];
    const int tid = threadIdx.x;
    const int t3 = blockIdx.x;                 // b*32 + wh
    const int hf = blockIdx.y;                 // 0..1
    const int h  = blockIdx.z;                 // 0..3
    const int bb = t3 >> 5, wh = t3 & 31;

    for (int idx = tid; idx < 1152; idx += 256) {
        int row = idx >> 3, ch = idx & 7;
        int ww = row / 9, t = row - ww * 9;
        int rr = t / 3, cc = t - rr * 3;
        size_t xrow = (size_t)bb * 9216 + (wh * 3 + rr) * 96 + hf * 48 + ww * 3 + cc;
        *(bf16x8*)&Ks[row * LQ + ch * 8] = *(const bf16x8*)(qkv + xrow * 768 + 256 + h * 64 + ch * 8);
        *(bf16x8*)&Vs[row * LQ + ch * 8] = *(const bf16x8*)(qkv + xrow * 768 + 512 + h * 64 + ch * 8);
    }
    __syncthreads();

#pragma unroll 1
    for (int pass = 0; pass < 2; ++pass) {
        int row;
        bool act;
        if (pass == 0) { row = tid >> 1;            act = true; }
        else           { row = 128 + (tid >> 1);    act = tid < 32; }
        if (act) {
            const int hc = tid & 1;
            const int w9 = (row / 9) * 9;
            int t = row - w9;
            int rr = t / 3, cc = t - rr * 3;
            size_t xrow = (size_t)bb * 9216 + (wh * 3 + rr) * 96 + hf * 48 + (w9 / 9) * 3 + cc;
            unsigned short* qp = qkv + xrow * 768 + h * 64 + hc * 32;
            float q[32];
#pragma unroll
            for (int g = 0; g < 4; ++g) {
                bf16x8 v = *(const bf16x8*)(qp + g * 8);
#pragma unroll
                for (int j = 0; j < 8; ++j) q[g * 8 + j] = bf2f(v[j]);
            }
            float s[9];
#pragma unroll
            for (int kk = 0; kk < 9; ++kk) {
                float acc = 0.f;
#pragma unroll
                for (int g = 0; g < 4; ++g) {
                    bf16x8 v = *(const bf16x8*)&Ks[(w9 + kk) * LQ + hc * 32 + g * 8];
#pragma unroll
                    for (int j = 0; j < 8; ++j) acc += q[g * 8 + j] * bf2f(v[j]);
                }
                s[kk] = acc;
            }
#pragma unroll
            for (int kk = 0; kk < 9; ++kk)
                s[kk] = (s[kk] + __shfl_xor(s[kk], 1)) * 0.125f;   // 1/sqrt(64)
            float m = s[0];
#pragma unroll
            for (int kk = 1; kk < 9; ++kk) m = fmaxf(m, s[kk]);
            float sum = 0.f;
#pragma unroll
            for (int kk = 0; kk < 9; ++kk) { s[kk] = __expf(s[kk] - m); sum += s[kk]; }
            float inv = 1.f / sum;
            float o[32];
#pragma unroll
            for (int d = 0; d < 32; ++d) o[d] = 0.f;
#pragma unroll
            for (int kk = 0; kk < 9; ++kk) {
                float pk = s[kk] * inv;
#pragma unroll
                for (int g = 0; g < 4; ++g) {
                    bf16x8 v = *(const bf16x8*)&Vs[(w9 + kk) * LQ + hc * 32 + g * 8];
#pragma unroll
                    for (int j = 0; j < 8; ++j) o[g * 8 + j] += pk * bf2f(v[j]);
                }
            }
#pragma unroll
            for (int grp = 0; grp < 4; ++grp) {
                u32x4 u;
#pragma unroll
                for (int e = 0; e < 4; ++e) {
                    int i0 = grp * 8 + e * 2;
                    u[e] = (unsigned)f2b(o[i0]) | ((unsigned)f2b(o[i0 + 1]) << 16);
                }
                *(u32x4*)(qp + grp * 8) = u;
            }
        }
    }
}

// ---------------- k_proj: m97-style GEMM [147456][256](stride 768)@[256][256]^T -> fp32 out ----------------
__global__ __launch_bounds__(256) void k_proj(
    const unsigned short* __restrict__ ain,    // attn-out = q region of qkv, row stride 768
    const unsigned short* __restrict__ wproj,  // bf16 [256][256]
    float* __restrict__ out)
{
    __shared__ unsigned short As[128 * 64];
    __shared__ unsigned short Bs[128 * 64];
    const int tid = threadIdx.x;
    const int wv = tid >> 6, ln = tid & 63;
    const int lr = ln & 15, lk = ln >> 4;
    const int l8 = ln >> 3, c8 = ln & 7;

    int b = blockIdx.x;                        // 2304 = 1152 m-tiles x 2 n-chunks
    int w = (b & 7) * 288 + (b >> 3);
    const size_t m0 = (size_t)(w >> 1) * 128;
    const int n0 = (w & 1) * 128;
    const int mq = (wv >> 1) * 64, nq = (wv & 1) * 64;

    f32x4 acc[4][4];
#pragma unroll
    for (int mi = 0; mi < 4; ++mi)
#pragma unroll
        for (int ni = 0; ni < 4; ++ni) {
            f32x4 z = {0.f, 0.f, 0.f, 0.f};
            acc[mi][ni] = z;
        }

#pragma unroll 1
    for (int ks = 0; ks < 4; ++ks) {
        const int k0 = ks * 64;
        __syncthreads();
#pragma unroll
        for (int i = 0; i < 4; ++i) {
            int r8 = i * 8 + l8;
            int sc = (c8 ^ (r8 & 7)) * 8;
            gl_lds16(ain   + (m0 + wv * 32 + r8) * 768 + k0 + sc,
                     &As[(wv * 32 + i * 8) * 64]);
            gl_lds16(wproj + (size_t)(n0 + wv * 32 + r8) * 256 + k0 + sc,
                     &Bs[(wv * 32 + i * 8) * 64]);
        }
        __syncthreads();

#pragma unroll
        for (int kk = 0; kk < 2; ++kk) {
            bf16x8 av[4], bv[4];
#pragma unroll
            for (int i = 0; i < 4; ++i) {
                int ar = mq + i * 16 + lr;
                av[i] = *(const bf16x8*)&As[ar * 64 + (((kk * 4 + lk) ^ (ar & 7)) * 8)];
                int br = nq + i * 16 + lr;
                bv[i] = *(const bf16x8*)&Bs[br * 64 + (((kk * 4 + lk) ^ (br & 7)) * 8)];
            }
#pragma unroll
            for (int mi = 0; mi < 4; ++mi)
#pragma unroll
                for (int ni = 0; ni < 4; ++ni)
                    acc[mi][ni] = __builtin_amdgcn_mfma_f32_16x16x32_bf16(bv[ni], av[mi], acc[mi][ni], 0, 0, 0);
        }
    }

#pragma unroll
    for (int mi = 0; mi < 4; ++mi) {
        const size_t row = m0 + mq + mi * 16 + lr;
#pragma unroll
        for (int ni = 0; ni < 4; ++ni)
            *(f32x4*)&out[row * 256 + n0 + nq + ni * 16 + lk * 4] = acc[mi][ni];
    }
}

// ==================== FALLBACK (round-3 kernels, ~76 MB ws) ====================

__device__ __forceinline__ int grow_of(int wbase, int row) {
    int wi = row / 9;
    int t  = row - wi * 9;
    int w  = wbase + wi;
    if (w >= 16384) return -1;
    int b = w >> 10, rem = w & 1023;
    int wh = rem >> 5, ww = rem & 31;
    int r = t / 3, c = t - r * 3;
    return b * 9216 + (wh * 3 + r) * 96 + ww * 3 + c;
}

__global__ __launch_bounds__(256) void k_winattn_fb(
    const float* __restrict__ x,
    const unsigned short* __restrict__ wqkv,
    unsigned short* __restrict__ aout)
{
    constexpr int LDA = 264;
    constexpr int LQ  = 68;
    __shared__ unsigned short As[64 * LDA];
    __shared__ unsigned short Qb[3][64 * LQ];
    __shared__ int rowmap[64];

    const int tid = threadIdx.x;
    const int wbase = blockIdx.x * 7;
    const int wv = tid >> 6, ln = tid & 63;
    const int lr = ln & 15, lk = ln >> 4;
    const int mw = wv >> 1, nw = wv & 1;

    if (tid < 64)
        rowmap[tid] = (tid < 63) ? grow_of(wbase, tid) : -1;
    __syncthreads();

    for (int idx = tid; idx < 64 * 32; idx += 256) {
        int row = idx >> 5, g = idx & 31;
        int gr = rowmap[row];
        bf16x8 v;
        if (gr >= 0) {
            const f32x4* p = (const f32x4*)(x + (size_t)gr * 256 + g * 8);
            f32x4 f0 = p[0], f1 = p[1];
#pragma unroll
            for (int j = 0; j < 4; ++j) {
                v[j]     = (short)f2b(f0[j]);
                v[4 + j] = (short)f2b(f1[j]);
            }
        } else {
#pragma unroll
            for (int j = 0; j < 8; ++j) v[j] = 0;
        }
        *(bf16x8*)&As[row * LDA + g * 8] = v;
    }
    __syncthreads();

#pragma unroll 1
    for (int h = 0; h < 4; ++h) {
#pragma unroll 1
        for (int part = 0; part < 3; ++part) {
            const int j0 = part * 256 + h * 64 + nw * 32;
            bf16x8 w[2][8];
#pragma unroll
            for (int ni = 0; ni < 2; ++ni)
#pragma unroll
                for (int kk = 0; kk < 8; ++kk)
                    w[ni][kk] = *(const bf16x8*)(wqkv + (size_t)(j0 + ni * 16 + lr) * 256 + kk * 32 + lk * 8);

            f32x4 acc[2][2];
#pragma unroll
            for (int mi = 0; mi < 2; ++mi)
#pragma unroll
                for (int ni = 0; ni < 2; ++ni) {
                    f32x4 z = {0.f, 0.f, 0.f, 0.f};
                    acc[mi][ni] = z;
                }
#pragma unroll
            for (int kk = 0; kk < 8; ++kk) {
                const int k0 = kk * 32 + lk * 8;
                bf16x8 a0 = *(const bf16x8*)&As[(mw * 32 + lr) * LDA + k0];
                bf16x8 a1 = *(const bf16x8*)&As[(mw * 32 + 16 + lr) * LDA + k0];
                acc[0][0] = __builtin_amdgcn_mfma_f32_16x16x32_bf16(w[0][kk], a0, acc[0][0], 0, 0, 0);
                acc[1][0] = __builtin_amdgcn_mfma_f32_16x16x32_bf16(w[0][kk], a1, acc[1][0], 0, 0, 0);
                acc[0][1] = __builtin_amdgcn_mfma_f32_16x16x32_bf16(w[1][kk], a0, acc[0][1], 0, 0, 0);
                acc[1][1] = __builtin_amdgcn_mfma_f32_16x16x32_bf16(w[1][kk], a1, acc[1][1], 0, 0, 0);
            }
#pragma unroll
            for (int mi = 0; mi < 2; ++mi)
#pragma unroll
                for (int ni = 0; ni < 2; ++ni) {
                    int row = mw * 32 + mi * 16 + lr;
                    int col = nw * 32 + ni * 16 + lk * 4;
                    u32x2 u;
                    u[0] = (unsigned)f2b(acc[mi][ni][0]) | ((unsigned)f2b(acc[mi][ni][1]) << 16);
                    u[1] = (unsigned)f2b(acc[mi][ni][2]) | ((unsigned)f2b(acc[mi][ni][3]) << 16);
                    *(u32x2*)&Qb[part][row * LQ + col] = u;
                }
        }
        __syncthreads();
        {
            const int row = wv * 16 + lr;
            const int c   = lk;
            if (row < 63) {
                const int w9 = (row / 9) * 9;
                float q[16];
#pragma unroll
                for (int g = 0; g < 4; ++g) {
                    bf16x4 v = *(const bf16x4*)&Qb[0][row * LQ + c * 16 + g * 4];
#pragma unroll
                    for (int j = 0; j < 4; ++j) q[g * 4 + j] = bf2f(v[j]);
                }
                float s[9];
#pragma unroll
                for (int kk = 0; kk < 9; ++kk) {
                    float t = 0.f;
#pragma unroll
                    for (int g = 0; g < 4; ++g) {
                        bf16x4 v = *(const bf16x4*)&Qb[1][(w9 + kk) * LQ + c * 16 + g * 4];
#pragma unroll
                        for (int j = 0; j < 4; ++j) t += q[g * 4 + j] * bf2f(v[j]);
                    }
                    s[kk] = t;
                }
#pragma unroll
                for (int kk = 0; kk < 9; ++kk) {
                    float t = s[kk];
                    t += __shfl_xor(t, 16);
                    t += __shfl_xor(t, 32);
                    s[kk] = t * 0.125f;
                }
                float m = s[0];
#pragma unroll
                for (int kk = 1; kk < 9; ++kk) m = fmaxf(m, s[kk]);
                float sum = 0.f;
#pragma unroll
                for (int kk = 0; kk < 9; ++kk) { s[kk] = __expf(s[kk] - m); sum += s[kk]; }
                float inv = 1.f / sum;
                float o[16];
#pragma unroll
                for (int d = 0; d < 16; ++d) o[d] = 0.f;
#pragma unroll
                for (int kk = 0; kk < 9; ++kk) {
                    float pk = s[kk] * inv;
#pragma unroll
                    for (int g = 0; g < 4; ++g) {
                        bf16x4 v = *(const bf16x4*)&Qb[2][(w9 + kk) * LQ + c * 16 + g * 4];
#pragma unroll
                        for (int j = 0; j < 4; ++j) o[g * 4 + j] += pk * bf2f(v[j]);
                    }
                }
                const int gr = rowmap[row];
                if (gr >= 0) {
#pragma unroll
                    for (int half = 0; half < 2; ++half) {
                        u32x4 u;
#pragma unroll
                        for (int e = 0; e < 4; ++e) {
                            int i0 = half * 8 + e * 2;
                            u[e] = (unsigned)f2b(o[i0]) | ((unsigned)f2b(o[i0 + 1]) << 16);
                        }
                        *(u32x4*)(aout + (size_t)gr * 256 + h * 64 + c * 16 + half * 8) = u;
                    }
                }
            }
        }
        __syncthreads();
    }
}

__global__ __launch_bounds__(256) void k_proj_fb(
    const unsigned short* __restrict__ ain,
    const unsigned short* __restrict__ wproj,
    float* __restrict__ out)
{
    const int tid = threadIdx.x;
    const int wv = tid >> 6, ln = tid & 63;
    const int lr = ln & 15, lk = ln >> 4;
    const size_t row0 = (size_t)blockIdx.x * 128;

    bf16x8 af[2][8];
#pragma unroll
    for (int mi = 0; mi < 2; ++mi) {
        const size_t row = row0 + wv * 32 + mi * 16 + lr;
#pragma unroll
        for (int kk = 0; kk < 8; ++kk)
            af[mi][kk] = *(const bf16x8*)(ain + row * 256 + kk * 32 + lk * 8);
    }
#pragma unroll
    for (int nc = 0; nc < 4; ++nc) {
        const int j0 = nc * 64;
        f32x4 acc[2][4];
#pragma unroll
        for (int mi = 0; mi < 2; ++mi)
#pragma unroll
            for (int ni = 0; ni < 4; ++ni) {
                f32x4 z = {0.f, 0.f, 0.f, 0.f};
                acc[mi][ni] = z;
            }
#pragma unroll
        for (int kk = 0; kk < 8; ++kk) {
            bf16x8 w[4];
#pragma unroll
            for (int ni = 0; ni < 4; ++ni)
                w[ni] = *(const bf16x8*)(wproj + (size_t)(j0 + ni * 16 + lr) * 256 + kk * 32 + lk * 8);
#pragma unroll
            for (int ni = 0; ni < 4; ++ni) {
                acc[0][ni] = __builtin_amdgcn_mfma_f32_16x16x32_bf16(w[ni], af[0][kk], acc[0][ni], 0, 0, 0);
                acc[1][ni] = __builtin_amdgcn_mfma_f32_16x16x32_bf16(w[ni], af[1][kk], acc[1][ni], 0, 0, 0);
            }
        }
#pragma unroll
        for (int mi = 0; mi < 2; ++mi) {
            const size_t row = row0 + wv * 32 + mi * 16 + lr;
#pragma unroll
            for (int ni = 0; ni < 4; ++ni)
                *(f32x4*)&out[row * 256 + j0 + ni * 16 + lk * 4] = acc[mi][ni];
        }
    }
}

extern "C" void kernel_launch(void* const* d_in, const int* in_sizes, int n_in,
                              void* d_out, int out_size, void* d_ws, size_t ws_size,
                              hipStream_t stream) {
    const float* x  = (const float*)d_in[0];
    const float* wq = (const float*)d_in[1];
    const float* wp = (const float*)d_in[2];
    unsigned short* wsb     = (unsigned short*)d_ws;
    unsigned short* wqkv_b  = wsb;                 // 196608
    unsigned short* wproj_b = wsb + 196608;        //  65536
    float* out = (float*)d_out;

    k_wconv<<<1024, 256, 0, stream>>>(wq, wp, wsb);

    const size_t need = 524288ULL + 147456ULL * 768ULL * 2ULL;   // weights + qkv (~227 MB)
    if (ws_size >= need) {
        unsigned short* qkv = wsb + 262144;                 // bf16 [147456][768]
        k_qkv6<<<6912, 256, 0, stream>>>(x, wqkv_b, qkv);
        k_attn<<<dim3(512, 2, 4), 256, 0, stream>>>(qkv);
        k_proj<<<2304, 256, 0, stream>>>(qkv, wproj_b, out);
    } else {
        unsigned short* aout = wsb + 262144;                // bf16 [147456][256]
        k_winattn_fb<<<2341, 256, 0, stream>>>(x, wqkv_b, aout);
        k_proj_fb  <<<1152, 256, 0, stream>>>(aout, wproj_b, out);
    }
}